// Round 20
// baseline (167.863 us; speedup 1.0000x reference)
//
#include <hip/hip_runtime.h>
#include <cstdint>

typedef unsigned long long u64;
typedef unsigned int u32;
typedef unsigned short u16;
typedef __attribute__((ext_vector_type(8))) u16 u16x8;
typedef __attribute__((ext_vector_type(4))) u16 u16x4;
typedef __attribute__((ext_vector_type(8))) _Float16 f16x8;
typedef __attribute__((ext_vector_type(4))) float f32x4;

#define T_LEN 2048
#define C_DIM 1024
#define H_NUM 16
#define M_ROWS 4096  // B*T
#define MB (1024ull * 1024ull)
// Single-pass fp16 q/k: dot error sigma ~3.3e-4. TAU = 9 sigma; all
// |q-1|<TAU get exact fp32 recompute (verified rounds 10-19).
#define TAU 3e-3f
#define FCAP 65536u
#define BLK_FCAP 512u

__device__ __forceinline__ u16 f2bf(float f) {
  unsigned u = __builtin_bit_cast(unsigned, f);
  return (u16)((u + 0x7FFFu + ((u >> 16) & 1u)) >> 16);
}
__device__ __forceinline__ u16 f2h(float f) {
  _Float16 h = (_Float16)f;
  return __builtin_bit_cast(u16, h);
}

__device__ __forceinline__ void async16(u16* lds, const u16* g) {
  __builtin_amdgcn_global_load_lds(
      (const __attribute__((address_space(1))) void*)g,
      (__attribute__((address_space(3))) void*)lds, 16, 0, 0);
}

// ---------------------------------------------------------------------------
// Split fp32 -> fp16 (x, Wq, Wk, Wv) and bf16 (Wo). Verified round 10.
// ---------------------------------------------------------------------------
__global__ __launch_bounds__(256) void split_all(
    const float* __restrict__ x,  const float* __restrict__ Wq,
    const float* __restrict__ Wk, const float* __restrict__ Wv,
    const float* __restrict__ Wo,
    u16* xh, u16* wq16, u16* wk16, u16* wv16, u16* woh, u32* flagcnt)
{
  const int i = blockIdx.x * 256 + threadIdx.x;
  if (i == 0) *flagcnt = 0;
  const float* src; u16* dst; int off; int isbf = 0;
  if      (i < 1048576) { src = x;  dst = xh;   off = i; }
  else if (i < 1310720) { src = Wq; dst = wq16; off = i - 1048576; }
  else if (i < 1572864) { src = Wk; dst = wk16; off = i - 1310720; }
  else if (i < 1835008) { src = Wv; dst = wv16; off = i - 1572864; }
  else                  { src = Wo; dst = woh;  off = i - 1835008; isbf = 1; }
  const float4 v = ((const float4*)src)[off];
  u16x4 h;
  if (isbf) {
    h[0] = f2bf(v.x); h[1] = f2bf(v.y); h[2] = f2bf(v.z); h[3] = f2bf(v.w);
  } else {
    h[0] = f2h(v.x);  h[1] = f2h(v.y);  h[2] = f2h(v.z);  h[3] = f2h(v.w);
  }
  ((u16x4*)dst)[off] = h;
}

// ---------------------------------------------------------------------------
// MERGED QKV single-pass fp16 MFMA GEMM (verified round 15): each block
// computes q, k AND v for the same (128-row, 64-col) window. 5 gload_lds +
// 24 MFMA per K-step.
// ---------------------------------------------------------------------------
__global__ __launch_bounds__(256) void mfma_qkv(
    const u16* __restrict__ A16,
    const u16* __restrict__ Bq16, const u16* __restrict__ Bk16,
    const u16* __restrict__ Bv16,
    const float* __restrict__ bq, const float* __restrict__ bk,
    const float* __restrict__ bv,
    u32* __restrict__ pbits, u32* __restrict__ flagcnt,
    u32* __restrict__ flaglist, u16* __restrict__ vT)
{
  __shared__ u16 Ahs[2][128][32];   // 16 KB
  __shared__ u16 Bqs[2][64][32];    //  8 KB
  __shared__ u16 Bks[2][64][32];    //  8 KB
  __shared__ u16 Bvs[2][64][32];    //  8 KB
  __shared__ u32 fls[2 + BLK_FCAP]; //  2 KB

  const int tid  = threadIdx.x;
  const int lane = tid & 63;
  const int w    = tid >> 6;
  const int wr   = w & 1;
  const int wc   = w >> 1;
  const int bm   = blockIdx.x * 128;
  const int bn   = blockIdx.y * 64;

  if (tid == 0) fls[0] = 0;

  f32x4 acc[3][4][2];
  #pragma unroll
  for (int s = 0; s < 3; ++s)
    #pragma unroll
    for (int mf = 0; mf < 4; ++mf)
      #pragma unroll
      for (int nf = 0; nf < 2; ++nf) acc[s][mf][nf] = (f32x4){0.f, 0.f, 0.f, 0.f};

  const int sr = lane >> 2;
  const int sc = lane & 3;

#define STG(DST, SRC, TB, R0, KT)                                          \
  async16(&DST[(R0)][0],                                                   \
          &SRC[(size_t)((TB) + (R0) + sr) * 1024 + (KT) +                  \
               ((sc ^ ((((R0) + sr) >> 1) & 3)) << 3)]);

#define STAGE(B_, KT)                        \
  {                                          \
    STG(Ahs[B_], A16, bm, w * 32, KT);       \
    STG(Ahs[B_], A16, bm, w * 32 + 16, KT);  \
    STG(Bqs[B_], Bq16, bn, w * 16, KT);      \
    STG(Bks[B_], Bk16, bn, w * 16, KT);      \
    STG(Bvs[B_], Bv16, bn, w * 16, KT);      \
  }

  STAGE(0, 0);
  __syncthreads();

  const int fr = lane & 15;
  const int fg = lane >> 4;
  int cur = 0;

  for (int kt = 0; kt < 1024; kt += 32) {
    if (kt + 32 < 1024) STAGE(cur ^ 1, kt + 32);

    f16x8 a_h[4];
    #pragma unroll
    for (int mf = 0; mf < 4; ++mf) {
      const int row = wr * 64 + mf * 16 + fr;
      const int cs = (fg ^ ((row >> 1) & 3)) << 3;
      a_h[mf] = __builtin_bit_cast(f16x8, *(const u16x8*)&Ahs[cur][row][cs]);
    }
    const int cs0 = (fg ^ (((wc * 32 + fr) >> 1) & 3)) << 3;
    const int cs1 = (fg ^ (((wc * 32 + 16 + fr) >> 1) & 3)) << 3;

    {
      f16x8 b0 = __builtin_bit_cast(f16x8, *(const u16x8*)&Bqs[cur][wc * 32 + fr][cs0]);
      f16x8 b1 = __builtin_bit_cast(f16x8, *(const u16x8*)&Bqs[cur][wc * 32 + 16 + fr][cs1]);
      #pragma unroll
      for (int mf = 0; mf < 4; ++mf) {
        acc[0][mf][0] = __builtin_amdgcn_mfma_f32_16x16x32_f16(a_h[mf], b0, acc[0][mf][0], 0, 0, 0);
        acc[0][mf][1] = __builtin_amdgcn_mfma_f32_16x16x32_f16(a_h[mf], b1, acc[0][mf][1], 0, 0, 0);
      }
    }
    {
      f16x8 b0 = __builtin_bit_cast(f16x8, *(const u16x8*)&Bks[cur][wc * 32 + fr][cs0]);
      f16x8 b1 = __builtin_bit_cast(f16x8, *(const u16x8*)&Bks[cur][wc * 32 + 16 + fr][cs1]);
      #pragma unroll
      for (int mf = 0; mf < 4; ++mf) {
        acc[1][mf][0] = __builtin_amdgcn_mfma_f32_16x16x32_f16(a_h[mf], b0, acc[1][mf][0], 0, 0, 0);
        acc[1][mf][1] = __builtin_amdgcn_mfma_f32_16x16x32_f16(a_h[mf], b1, acc[1][mf][1], 0, 0, 0);
      }
    }
    {
      f16x8 b0 = __builtin_bit_cast(f16x8, *(const u16x8*)&Bvs[cur][wc * 32 + fr][cs0]);
      f16x8 b1 = __builtin_bit_cast(f16x8, *(const u16x8*)&Bvs[cur][wc * 32 + 16 + fr][cs1]);
      #pragma unroll
      for (int mf = 0; mf < 4; ++mf) {
        acc[2][mf][0] = __builtin_amdgcn_mfma_f32_16x16x32_f16(a_h[mf], b0, acc[2][mf][0], 0, 0, 0);
        acc[2][mf][1] = __builtin_amdgcn_mfma_f32_16x16x32_f16(a_h[mf], b1, acc[2][mf][1], 0, 0, 0);
      }
    }
    __syncthreads();
    cur ^= 1;
  }
#undef STAGE
#undef STG

  const int head = bn >> 6;
  #pragma unroll
  for (int sel = 0; sel < 2; ++sel) {
    const float* bias = sel ? bk : bq;
    const int c0 = bn + wc * 32 + fr;
    const int c1 = c0 + 16;
    const float bb0 = bias[c0];
    const float bb1 = bias[c1];
    #pragma unroll
    for (int mf = 0; mf < 4; ++mf) {
      const int row0 = bm + wr * 64 + mf * 16;
      #pragma unroll
      for (int j = 0; j < 4; ++j) {
        const float v0 = acc[sel][mf][0][j] + bb0;
        const float v1 = acc[sel][mf][1][j] + bb1;
        const u64 b0 = __ballot(v0 > 1.0f);
        const u64 b1 = __ballot(v1 > 1.0f);
        const int m = row0 + fg * 4 + j;
        if (fr == 0) {
          const u32 mask = (u32)((b0 >> (fg * 16)) & 0xFFFFu)
                         | ((u32)((b1 >> (fg * 16)) & 0xFFFFu) << 16);
          pbits[(((size_t)sel * 4096 + m) * 16 + head) * 2 + wc] = mask;
        }
        if (__builtin_fabsf(v0 - 1.0f) < TAU) {
          const u32 s = atomicAdd(&fls[0], 1u);   // LDS atomic
          if (s < BLK_FCAP) fls[2 + s] = ((u32)sel << 22) | ((u32)m << 10) | (u32)c0;
        }
        if (__builtin_fabsf(v1 - 1.0f) < TAU) {
          const u32 s = atomicAdd(&fls[0], 1u);
          if (s < BLK_FCAP) fls[2 + s] = ((u32)sel << 22) | ((u32)m << 10) | (u32)c1;
        }
      }
    }
  }
  __syncthreads();
  {
    const u32 cnt = fls[0] < BLK_FCAP ? fls[0] : BLK_FCAP;
    if (tid == 0) fls[1] = atomicAdd(flagcnt, cnt);  // ONE global atomic/block
    __syncthreads();
    const u32 base = fls[1];
    for (u32 i = tid; i < cnt; i += 256) {
      const u32 pos = base + i;
      if (pos < FCAP) flaglist[pos] = fls[2 + i];
    }
  }

  #pragma unroll
  for (int mf = 0; mf < 4; ++mf) {
    const int row0 = bm + wr * 64 + mf * 16 + fg * 4;
    #pragma unroll
    for (int nf = 0; nf < 2; ++nf) {
      const int col = bn + wc * 32 + nf * 16 + fr;
      const float bbv = bv[col];
      const int bb_ = row0 >> 11, t0 = row0 & 2047;
      const int hh = col >> 6, dd = col & 63;
      u16x4 o;
      o[0] = f2bf(acc[2][mf][nf][0] + bbv);
      o[1] = f2bf(acc[2][mf][nf][1] + bbv);
      o[2] = f2bf(acc[2][mf][nf][2] + bbv);
      o[3] = f2bf(acc[2][mf][nf][3] + bbv);
      *(u16x4*)&vT[(((size_t)(bb_ * 16 + hh)) * 64 + dd) * 2048 + t0] = o;
    }
  }
}

// ---------------------------------------------------------------------------
// Recompute near-threshold q/k entries with exact fp32 dot (verified).
// ---------------------------------------------------------------------------
__global__ __launch_bounds__(256) void fix_bits(
    const float* __restrict__ x,
    const float* __restrict__ Wq, const float* __restrict__ Wk,
    const float* __restrict__ bq, const float* __restrict__ bk,
    u32* __restrict__ pbits,
    const u32* __restrict__ flagcnt, const u32* __restrict__ flaglist)
{
  u32 cnt = *flagcnt;
  if (cnt > FCAP) cnt = FCAP;
  const int lane = threadIdx.x & 63;
  const u32 wid  = (blockIdx.x * 256 + threadIdx.x) >> 6;
  const u32 nw   = gridDim.x * 4;
  for (u32 i = wid; i < cnt; i += nw) {
    const u32 e = flaglist[i];
    const int which = e >> 22;
    const int m = (e >> 10) & 4095;
    const int n = e & 1023;
    const float* W    = which ? Wk : Wq;
    const float* bias = which ? bk : bq;
    float s = 0.f;
    #pragma unroll
    for (int j = 0; j < 16; ++j)
      s += x[(size_t)m * 1024 + lane + j * 64] * W[(size_t)n * 1024 + lane + j * 64];
    #pragma unroll
    for (int off = 32; off > 0; off >>= 1) s += __shfl_xor(s, off);
    const float val = s + bias[n];
    if (lane == 0) {
      const size_t idx = (((size_t)which * 4096 + m) * 16 + (n >> 6)) * 2 + ((n >> 5) & 1);
      const u32 bit = 1u << (n & 31);
      const bool oldb = (pbits[idx] >> (n & 31)) & 1u;
      const bool newb = val > 1.0f;
      if (oldb != newb) atomicXor(&pbits[idx], bit);
    }
  }
}

// ---------------------------------------------------------------------------
// MFMA attention, round 20 = verified round-18 kernel (dbuf vtb, single
// barrier/tile, 1-D wt_tab[65], in-register A-fragments, ones-MFMA Z, XCD
// swizzle, setprio, T14 V prefetch) + ONE change: kbt LDS array DELETED —
// each thread prefetches ITS OWN 8 key-bit u64s for the next tile into
// registers directly from global pbits (L2-resident 0.5MB; fg-group lanes
// broadcast-read the same 64B). Removes 8 ds_read_b64 + 1 write per
// thread-tile (~35% of the LDS-pipe load that bounds this kernel). Unlike
// round-17's failed direct-global V, these loads feed the weight VALU phase
// (ample overlap) and are prefetched a full tile ahead. Bit-identical.
// (Round-19 2-D table reverted: doubled bank conflicts.)
// ---------------------------------------------------------------------------
__global__ __launch_bounds__(256) void attn_mfma(
    const u32* __restrict__ pbits, const u16* __restrict__ vT,
    u16* __restrict__ oh)
{
  __shared__ u16 vtb[2][64][72];
  __shared__ u32 wt_tab[65];

  const int tid = threadIdx.x, lane = tid & 63, w = tid >> 6;
  const int bid = ((blockIdx.x & 7) << 7) | (blockIdx.x >> 3);  // XCD swizzle
  const int qt = bid & 31, bh = bid >> 5, b = bh >> 4, h = bh & 15;

  const int fr = lane & 15, fg = lane >> 4;

  if (tid < 65)
    wt_tab[tid] = __builtin_bit_cast(u32, exp2f((float)tid * 0.1803368801f));

  const int qm = b * T_LEN + qt * 64 + w * 16 + fr;
  const size_t qbase = (((size_t)qm) * 16 + h) * 2;
  const u32 qlo = pbits[qbase];
  const u32 qhi = pbits[qbase + 1];

  f32x4 acc[4];
  #pragma unroll
  for (int nf = 0; nf < 4; ++nf) acc[nf] = (f32x4){0.f, 0.f, 0.f, 0.f};
  f32x4 acc_z = (f32x4){0.f, 0.f, 0.f, 0.f};

  u16x8 ones;
  #pragma unroll
  for (int j = 0; j < 8; ++j) ones[j] = 0x3F80;  // bf16 1.0

  const u16* vbase = vT + (size_t)bh * 64 * T_LEN;
  const int sd = tid >> 2, sk = (tid & 3) << 3;

  // Key-bit base for THIS thread's 8 keys (keys fg*8.. within each tile):
  // pbits index for key km: ((4096 + km)*16 + h)*2, u64-aligned pair.
  const u32* kpb = pbits + (((size_t)(4096 + b * T_LEN)) * 16 + h) * 2;

  // T14 prefetch registers
  u16x8 r0, r1;
  u64 kreg[8], knxt[8];
#define VLOAD(KT)                                                       \
  {                                                                     \
    r0 = *(const u16x8*)&vbase[(size_t)sd * T_LEN + (KT) + sk];         \
    r1 = *(const u16x8*)&vbase[(size_t)sd * T_LEN + (KT) + sk + 32];    \
  }
#define KLOAD(DST, KT)                                                  \
  {                                                                     \
    _Pragma("unroll")                                                   \
    for (int i_ = 0; i_ < 8; ++i_)                                      \
      DST[i_] = *(const u64*)&kpb[(size_t)((KT) + fg * 8 + i_) * 32];   \
  }

  VLOAD(0);
  KLOAD(kreg, 0);

  int cur = 0;
  for (int kt = 0; kt < T_LEN; kt += 64) {
    *(u16x8*)&vtb[cur][sd][sk]      = r0;
    *(u16x8*)&vtb[cur][sd][sk + 32] = r1;
    if (kt + 64 < T_LEN) { VLOAD(kt + 64); KLOAD(knxt, kt + 64); }
    __syncthreads();   // single barrier per tile (vtb dbuf pipeline)

    __builtin_amdgcn_s_setprio(1);
    #pragma unroll
    for (int ks = 0; ks < 2; ++ks) {
      // my 8 weights this ks-half: keys ks*32 + fg*8 .. +7?  NO — per the
      // verified fragment layout my keys are ks*32+fg*8..+7; kreg holds
      // tile-local keys fg*8..+7 and fg*8+32..+39 via two KLOAD halves.
      u16x8 af;
      u32* afw = (u32*)&af;
      #pragma unroll
      for (int p = 0; p < 4; ++p) {
        const u64 kb0 = kreg[ks * 4 + p] & 0xFFFFFFFFull;   // placeholder
        (void)kb0;
        const u64 k0 = kreg[ks * 4 + p];
        // each kreg slot i holds key fg*8+i of... see KLOAD2 below
        (void)k0;
        afw[p] = 0;
      }
      // real computation below
      #pragma unroll
      for (int p = 0; p < 4; ++p) {
        const int i0 = ks * 4 + p;   // not used; see corrected indexing
        (void)i0;
      }
      // --- corrected: weights from kreg2 (see KLOAD2) ---
      (void)afw;
      #pragma unroll
      for (int nf = 0; nf < 4; ++nf) {
        const u16x8 bfv = *(const u16x8*)&vtb[cur][nf * 16 + fr][ks * 32 + fg * 8];
        acc[nf] = __builtin_amdgcn_mfma_f32_16x16x32_bf16(af, bfv, acc[nf], 0, 0, 0);
      }
      acc_z = __builtin_amdgcn_mfma_f32_16x16x32_bf16(af, ones, acc_z, 0, 0, 0);
    }
    __builtin_amdgcn_s_setprio(0);
    #pragma unroll
    for (int i_ = 0; i_ < 8; ++i_) kreg[i_] = knxt[i_];
    cur ^= 1;
  }
#undef VLOAD
#undef KLOAD

  float invZ[4];
  #pragma unroll
  for (int j = 0; j < 4; ++j) invZ[j] = 1.0f / acc_z[j];

  #pragma unroll
  for (int nf = 0; nf < 4; ++nf) {
    const int col = h * 64 + nf * 16 + fr;
    #pragma unroll
    for (int j = 0; j < 4; ++j) {
      const int qrow = w * 16 + fg * 4 + j;
      const float o = acc[nf][j] * invZ[j];
      const size_t gq = (size_t)b * T_LEN + qt * 64 + qrow;
      oh[gq * 1024 + col] = f2bf(o);
    }
  }
}

// NOTE: the block above contained an indexing confusion while drafting; the
// actual shipped kernel is attn_mfma_v2 below, used by kernel_launch. The
// keys needed per thread are ks*32 + fg*8 + 0..7 for ks in {0,1}: exactly
// 16 keys = kregA[8] (ks=0 range fg*8..+7 + 0) and kregB[8] (ks=1 range
// fg*8..+7 + 32). Both prefetched per tile.
__global__ __launch_bounds__(256) void attn_mfma_v2(
    const u32* __restrict__ pbits, const u16* __restrict__ vT,
    u16* __restrict__ oh)
{
  __shared__ u16 vtb[2][64][72];
  __shared__ u32 wt_tab[65];

  const int tid = threadIdx.x, lane = tid & 63, w = tid >> 6;
  const int bid = ((blockIdx.x & 7) << 7) | (blockIdx.x >> 3);  // XCD swizzle
  const int qt = bid & 31, bh = bid >> 5, b = bh >> 4, h = bh & 15;

  const int fr = lane & 15, fg = lane >> 4;

  if (tid < 65)
    wt_tab[tid] = __builtin_bit_cast(u32, exp2f((float)tid * 0.1803368801f));

  const int qm = b * T_LEN + qt * 64 + w * 16 + fr;
  const size_t qbase = (((size_t)qm) * 16 + h) * 2;
  const u32 qlo = pbits[qbase];
  const u32 qhi = pbits[qbase + 1];

  f32x4 acc[4];
  #pragma unroll
  for (int nf = 0; nf < 4; ++nf) acc[nf] = (f32x4){0.f, 0.f, 0.f, 0.f};
  f32x4 acc_z = (f32x4){0.f, 0.f, 0.f, 0.f};

  u16x8 ones;
  #pragma unroll
  for (int j = 0; j < 8; ++j) ones[j] = 0x3F80;  // bf16 1.0

  const u16* vbase = vT + (size_t)bh * 64 * T_LEN;
  const int sd = tid >> 2, sk = (tid & 3) << 3;

  // key-bit pointer: key km -> kpb[km * 32] (u32 units; 8B-aligned pair)
  const u32* kpb = pbits + (((size_t)(4096 + b * T_LEN)) * 16 + h) * 2;

  u16x8 r0, r1;
  u64 ka[8], kb_[8], na[8], nb[8];   // current/next, ks=0 and ks=1 key sets
#define VLOAD(KT)                                                       \
  {                                                                     \
    r0 = *(const u16x8*)&vbase[(size_t)sd * T_LEN + (KT) + sk];         \
    r1 = *(const u16x8*)&vbase[(size_t)sd * T_LEN + (KT) + sk + 32];    \
  }
#define KLOAD(DA, DB, KT)                                               \
  {                                                                     \
    _Pragma("unroll")                                                   \
    for (int i_ = 0; i_ < 8; ++i_) {                                    \
      DA[i_] = *(const u64*)&kpb[(size_t)((KT) + fg * 8 + i_) * 32];    \
      DB[i_] = *(const u64*)&kpb[(size_t)((KT) + 32 + fg * 8 + i_) * 32]; \
    }                                                                   \
  }

  VLOAD(0);
  KLOAD(ka, kb_, 0);

  int cur = 0;
  for (int kt = 0; kt < T_LEN; kt += 64) {
    *(u16x8*)&vtb[cur][sd][sk]      = r0;
    *(u16x8*)&vtb[cur][sd][sk + 32] = r1;
    if (kt + 64 < T_LEN) { VLOAD(kt + 64); KLOAD(na, nb, kt + 64); }
    __syncthreads();   // single barrier per tile (vtb dbuf pipeline)

    __builtin_amdgcn_s_setprio(1);
    #pragma unroll
    for (int ks = 0; ks < 2; ++ks) {
      u16x8 af;
      u32* afw = (u32*)&af;
      #pragma unroll
      for (int p = 0; p < 4; ++p) {
        const u64 k0 = ks ? kb_[p * 2] : ka[p * 2];
        const u64 k1 = ks ? kb_[p * 2 + 1] : ka[p * 2 + 1];
        const int mm0 = __builtin_popcount(qlo & (u32)k0)
                      + __builtin_popcount(qhi & (u32)(k0 >> 32));
        const int mm1 = __builtin_popcount(qlo & (u32)k1)
                      + __builtin_popcount(qhi & (u32)(k1 >> 32));
        const u32 t0 = wt_tab[mm0];
        const u32 t1 = wt_tab[mm1];
        afw[p] = (t1 & 0xFFFF0000u) | (t0 >> 16);
      }
      #pragma unroll
      for (int nf = 0; nf < 4; ++nf) {
        const u16x8 bfv = *(const u16x8*)&vtb[cur][nf * 16 + fr][ks * 32 + fg * 8];
        acc[nf] = __builtin_amdgcn_mfma_f32_16x16x32_bf16(af, bfv, acc[nf], 0, 0, 0);
      }
      acc_z = __builtin_amdgcn_mfma_f32_16x16x32_bf16(af, ones, acc_z, 0, 0, 0);
    }
    __builtin_amdgcn_s_setprio(0);
    #pragma unroll
    for (int i_ = 0; i_ < 8; ++i_) { ka[i_] = na[i_]; kb_[i_] = nb[i_]; }
    cur ^= 1;
  }
#undef VLOAD
#undef KLOAD

  float invZ[4];
  #pragma unroll
  for (int j = 0; j < 4; ++j) invZ[j] = 1.0f / acc_z[j];

  #pragma unroll
  for (int nf = 0; nf < 4; ++nf) {
    const int col = h * 64 + nf * 16 + fr;
    #pragma unroll
    for (int j = 0; j < 4; ++j) {
      const int qrow = w * 16 + fg * 4 + j;
      const float o = acc[nf][j] * invZ[j];
      const size_t gq = (size_t)b * T_LEN + qt * 64 + qrow;
      oh[gq * 1024 + col] = f2bf(o);
    }
  }
}

// ---------------------------------------------------------------------------
// Out projection: single-pass bf16 MFMA (verified round 6).
// ---------------------------------------------------------------------------
__global__ __launch_bounds__(256) void mfma_out(
    const u16* __restrict__ Ah, const u16* __restrict__ Bh,
    const float* __restrict__ bias, float* __restrict__ out)
{
  __shared__ u16 Ahs[2][128][32];
  __shared__ u16 Bhs[2][64][32];

  const int tid  = threadIdx.x;
  const int lane = tid & 63;
  const int w    = tid >> 6;
  const int wr   = w & 1;
  const int wc   = w >> 1;
  const int bm   = blockIdx.x * 128;
  const int bn   = blockIdx.y * 64;

  f32x4 acc[4][2];
  #pragma unroll
  for (int mf = 0; mf < 4; ++mf)
    #pragma unroll
    for (int nf = 0; nf < 2; ++nf) acc[mf][nf] = (f32x4){0.f, 0.f, 0.f, 0.f};

  const int sr = lane >> 2;
  const int sc = lane & 3;

#define STG(DST, SRC, TB, R0, KT)                                          \
  async16(&DST[(R0)][0],                                                   \
          &SRC[(size_t)((TB) + (R0) + sr) * 1024 + (KT) +                  \
               ((sc ^ ((((R0) + sr) >> 1) & 3)) << 3)]);

#define STAGE(B_, KT)                        \
  {                                          \
    STG(Ahs[B_], Ah, bm, w * 32, KT);        \
    STG(Ahs[B_], Ah, bm, w * 32 + 16, KT);   \
    STG(Bhs[B_], Bh, bn, w * 16, KT);        \
  }

  STAGE(0, 0);
  __syncthreads();

  const int fr = lane & 15;
  const int fg = lane >> 4;
  int cur = 0;

  for (int kt = 0; kt < 1024; kt += 32) {
    if (kt + 32 < 1024) STAGE(cur ^ 1, kt + 32);

    u16x8 a_h[4], b_h[2];
    #pragma unroll
    for (int mf = 0; mf < 4; ++mf) {
      const int row = wr * 64 + mf * 16 + fr;
      const int cs = (fg ^ ((row >> 1) & 3)) << 3;
      a_h[mf] = *(const u16x8*)&Ahs[cur][row][cs];
    }
    #pragma unroll
    for (int nf = 0; nf < 2; ++nf) {
      const int col = wc * 32 + nf * 16 + fr;
      const int cs = (fg ^ ((col >> 1) & 3)) << 3;
      b_h[nf] = *(const u16x8*)&Bhs[cur][col][cs];
    }
    #pragma unroll
    for (int mf = 0; mf < 4; ++mf)
      #pragma unroll
      for (int nf = 0; nf < 2; ++nf)
        acc[mf][nf] = __builtin_amdgcn_mfma_f32_16x16x32_bf16(a_h[mf], b_h[nf], acc[mf][nf], 0, 0, 0);
    __syncthreads();
    cur ^= 1;
  }
#undef STAGE
#undef STG

  #pragma unroll
  for (int mf = 0; mf < 4; ++mf) {
    const int row0 = bm + wr * 64 + mf * 16 + fg * 4;
    #pragma unroll
    for (int nf = 0; nf < 2; ++nf) {
      const int col = bn + wc * 32 + nf * 16 + fr;
      const float bb = bias[col];
      #pragma unroll
      for (int j = 0; j < 4; ++j)
        out[(size_t)(row0 + j) * 1024 + col] = acc[mf][nf][j] + bb;
    }
  }
}

// ---------------------------------------------------------------------------
extern "C" void kernel_launch(void* const* d_in, const int* in_sizes, int n_in,
                              void* d_out, int out_size, void* d_ws, size_t ws_size,
                              hipStream_t stream) {
  const float* x  = (const float*)d_in[0];
  const float* Wq = (const float*)d_in[1];
  const float* bq = (const float*)d_in[2];
  const float* Wk = (const float*)d_in[3];
  const float* bk = (const float*)d_in[4];
  const float* Wv = (const float*)d_in[5];
  const float* bv = (const float*)d_in[6];
  const float* Wo = (const float*)d_in[7];
  const float* bo = (const float*)d_in[8];
  float* out = (float*)d_out;

  char* ws = (char*)d_ws;
  u16* oh   = (u16*)ws;                // [0,8MB)
  u16* xh   = (u16*)(ws + 16 * MB);    // fp16 x, 8MB
  u16* vT   = (u16*)(ws + 32 * MB);    // bf16 vT, 8MB
  u16* Woh  = (u16*)(ws + 40 * MB);    // bf16 Wo, 2MB
  u32* pbits = (u32*)(ws + 44 * MB);
  u32* flagcnt  = (u32*)(ws + 45 * MB);
  u32* flaglist = (u32*)(ws + 45 * MB + 256);

  // d_out doubles as scratch for q/k/v fp16 weights (dead before out-proj).
  char* dob = (char*)d_out;
  u16* Wq16 = (u16*)dob;
  u16* Wk16 = (u16*)(dob + 2 * MB);
  u16* Wv16 = (u16*)(dob + 4 * MB);

  split_all<<<8192, 256, 0, stream>>>(x, Wq, Wk, Wv, Wo,
                                      xh, Wq16, Wk16, Wv16, Woh, flagcnt);

  dim3 g1(M_ROWS / 128, 1024 / 64);   // merged: one block does q+k+v
  mfma_qkv<<<g1, 256, 0, stream>>>(xh, Wq16, Wk16, Wv16,
                                   bq, bk, bv, pbits, flagcnt, flaglist, vT);

  fix_bits<<<256, 256, 0, stream>>>(x, Wq, Wk, bq, bk, pbits, flagcnt, flaglist);

  attn_mfma_v2<<<32 * 32, 256, 0, stream>>>(pbits, vT, oh);

  dim3 g2(M_ROWS / 128, 1024 / 64);
  mfma_out<<<g2, 256, 0, stream>>>(oh, Woh, bo, out);
}

// Round 21
// 140.602 us; speedup vs baseline: 1.1939x; 1.1939x over previous
//
#include <hip/hip_runtime.h>
#include <cstdint>

typedef unsigned long long u64;
typedef unsigned int u32;
typedef unsigned short u16;
typedef __attribute__((ext_vector_type(8))) u16 u16x8;
typedef __attribute__((ext_vector_type(4))) u16 u16x4;
typedef __attribute__((ext_vector_type(8))) _Float16 f16x8;
typedef __attribute__((ext_vector_type(4))) float f32x4;

#define T_LEN 2048
#define C_DIM 1024
#define H_NUM 16
#define M_ROWS 4096  // B*T
#define MB (1024ull * 1024ull)
// Single-pass fp16 q/k: dot error sigma ~3.3e-4. TAU = 9 sigma; all
// |q-1|<TAU get exact fp32 recompute (verified rounds 10-20).
#define TAU 3e-3f
#define FCAP 65536u
#define BLK_FCAP 512u

__device__ __forceinline__ u16 f2bf(float f) {
  unsigned u = __builtin_bit_cast(unsigned, f);
  return (u16)((u + 0x7FFFu + ((u >> 16) & 1u)) >> 16);
}
__device__ __forceinline__ u16 f2h(float f) {
  _Float16 h = (_Float16)f;
  return __builtin_bit_cast(u16, h);
}

__device__ __forceinline__ void async16(u16* lds, const u16* g) {
  __builtin_amdgcn_global_load_lds(
      (const __attribute__((address_space(1))) void*)g,
      (__attribute__((address_space(3))) void*)lds, 16, 0, 0);
}

// ---------------------------------------------------------------------------
// Split fp32 -> fp16 (x, Wq, Wk, Wv) and bf16 (Wo). Verified round 10.
// ---------------------------------------------------------------------------
__global__ __launch_bounds__(256) void split_all(
    const float* __restrict__ x,  const float* __restrict__ Wq,
    const float* __restrict__ Wk, const float* __restrict__ Wv,
    const float* __restrict__ Wo,
    u16* xh, u16* wq16, u16* wk16, u16* wv16, u16* woh, u32* flagcnt)
{
  const int i = blockIdx.x * 256 + threadIdx.x;
  if (i == 0) *flagcnt = 0;
  const float* src; u16* dst; int off; int isbf = 0;
  if      (i < 1048576) { src = x;  dst = xh;   off = i; }
  else if (i < 1310720) { src = Wq; dst = wq16; off = i - 1048576; }
  else if (i < 1572864) { src = Wk; dst = wk16; off = i - 1310720; }
  else if (i < 1835008) { src = Wv; dst = wv16; off = i - 1572864; }
  else                  { src = Wo; dst = woh;  off = i - 1835008; isbf = 1; }
  const float4 v = ((const float4*)src)[off];
  u16x4 h;
  if (isbf) {
    h[0] = f2bf(v.x); h[1] = f2bf(v.y); h[2] = f2bf(v.z); h[3] = f2bf(v.w);
  } else {
    h[0] = f2h(v.x);  h[1] = f2h(v.y);  h[2] = f2h(v.z);  h[3] = f2h(v.w);
  }
  ((u16x4*)dst)[off] = h;
}

// ---------------------------------------------------------------------------
// MERGED QKV single-pass fp16 MFMA GEMM (verified round 15): each block
// computes q, k AND v for the same (128-row, 64-col) window. 5 gload_lds +
// 24 MFMA per K-step.
// ---------------------------------------------------------------------------
__global__ __launch_bounds__(256) void mfma_qkv(
    const u16* __restrict__ A16,
    const u16* __restrict__ Bq16, const u16* __restrict__ Bk16,
    const u16* __restrict__ Bv16,
    const float* __restrict__ bq, const float* __restrict__ bk,
    const float* __restrict__ bv,
    u32* __restrict__ pbits, u32* __restrict__ flagcnt,
    u32* __restrict__ flaglist, u16* __restrict__ vT)
{
  __shared__ u16 Ahs[2][128][32];   // 16 KB
  __shared__ u16 Bqs[2][64][32];    //  8 KB
  __shared__ u16 Bks[2][64][32];    //  8 KB
  __shared__ u16 Bvs[2][64][32];    //  8 KB
  __shared__ u32 fls[2 + BLK_FCAP]; //  2 KB

  const int tid  = threadIdx.x;
  const int lane = tid & 63;
  const int w    = tid >> 6;
  const int wr   = w & 1;
  const int wc   = w >> 1;
  const int bm   = blockIdx.x * 128;
  const int bn   = blockIdx.y * 64;

  if (tid == 0) fls[0] = 0;

  f32x4 acc[3][4][2];
  #pragma unroll
  for (int s = 0; s < 3; ++s)
    #pragma unroll
    for (int mf = 0; mf < 4; ++mf)
      #pragma unroll
      for (int nf = 0; nf < 2; ++nf) acc[s][mf][nf] = (f32x4){0.f, 0.f, 0.f, 0.f};

  const int sr = lane >> 2;
  const int sc = lane & 3;

#define STG(DST, SRC, TB, R0, KT)                                          \
  async16(&DST[(R0)][0],                                                   \
          &SRC[(size_t)((TB) + (R0) + sr) * 1024 + (KT) +                  \
               ((sc ^ ((((R0) + sr) >> 1) & 3)) << 3)]);

#define STAGE(B_, KT)                        \
  {                                          \
    STG(Ahs[B_], A16, bm, w * 32, KT);       \
    STG(Ahs[B_], A16, bm, w * 32 + 16, KT);  \
    STG(Bqs[B_], Bq16, bn, w * 16, KT);      \
    STG(Bks[B_], Bk16, bn, w * 16, KT);      \
    STG(Bvs[B_], Bv16, bn, w * 16, KT);      \
  }

  STAGE(0, 0);
  __syncthreads();

  const int fr = lane & 15;
  const int fg = lane >> 4;
  int cur = 0;

  for (int kt = 0; kt < 1024; kt += 32) {
    if (kt + 32 < 1024) STAGE(cur ^ 1, kt + 32);

    f16x8 a_h[4];
    #pragma unroll
    for (int mf = 0; mf < 4; ++mf) {
      const int row = wr * 64 + mf * 16 + fr;
      const int cs = (fg ^ ((row >> 1) & 3)) << 3;
      a_h[mf] = __builtin_bit_cast(f16x8, *(const u16x8*)&Ahs[cur][row][cs]);
    }
    const int cs0 = (fg ^ (((wc * 32 + fr) >> 1) & 3)) << 3;
    const int cs1 = (fg ^ (((wc * 32 + 16 + fr) >> 1) & 3)) << 3;

    {
      f16x8 b0 = __builtin_bit_cast(f16x8, *(const u16x8*)&Bqs[cur][wc * 32 + fr][cs0]);
      f16x8 b1 = __builtin_bit_cast(f16x8, *(const u16x8*)&Bqs[cur][wc * 32 + 16 + fr][cs1]);
      #pragma unroll
      for (int mf = 0; mf < 4; ++mf) {
        acc[0][mf][0] = __builtin_amdgcn_mfma_f32_16x16x32_f16(a_h[mf], b0, acc[0][mf][0], 0, 0, 0);
        acc[0][mf][1] = __builtin_amdgcn_mfma_f32_16x16x32_f16(a_h[mf], b1, acc[0][mf][1], 0, 0, 0);
      }
    }
    {
      f16x8 b0 = __builtin_bit_cast(f16x8, *(const u16x8*)&Bks[cur][wc * 32 + fr][cs0]);
      f16x8 b1 = __builtin_bit_cast(f16x8, *(const u16x8*)&Bks[cur][wc * 32 + 16 + fr][cs1]);
      #pragma unroll
      for (int mf = 0; mf < 4; ++mf) {
        acc[1][mf][0] = __builtin_amdgcn_mfma_f32_16x16x32_f16(a_h[mf], b0, acc[1][mf][0], 0, 0, 0);
        acc[1][mf][1] = __builtin_amdgcn_mfma_f32_16x16x32_f16(a_h[mf], b1, acc[1][mf][1], 0, 0, 0);
      }
    }
    {
      f16x8 b0 = __builtin_bit_cast(f16x8, *(const u16x8*)&Bvs[cur][wc * 32 + fr][cs0]);
      f16x8 b1 = __builtin_bit_cast(f16x8, *(const u16x8*)&Bvs[cur][wc * 32 + 16 + fr][cs1]);
      #pragma unroll
      for (int mf = 0; mf < 4; ++mf) {
        acc[2][mf][0] = __builtin_amdgcn_mfma_f32_16x16x32_f16(a_h[mf], b0, acc[2][mf][0], 0, 0, 0);
        acc[2][mf][1] = __builtin_amdgcn_mfma_f32_16x16x32_f16(a_h[mf], b1, acc[2][mf][1], 0, 0, 0);
      }
    }
    __syncthreads();
    cur ^= 1;
  }
#undef STAGE
#undef STG

  const int head = bn >> 6;
  #pragma unroll
  for (int sel = 0; sel < 2; ++sel) {
    const float* bias = sel ? bk : bq;
    const int c0 = bn + wc * 32 + fr;
    const int c1 = c0 + 16;
    const float bb0 = bias[c0];
    const float bb1 = bias[c1];
    #pragma unroll
    for (int mf = 0; mf < 4; ++mf) {
      const int row0 = bm + wr * 64 + mf * 16;
      #pragma unroll
      for (int j = 0; j < 4; ++j) {
        const float v0 = acc[sel][mf][0][j] + bb0;
        const float v1 = acc[sel][mf][1][j] + bb1;
        const u64 b0 = __ballot(v0 > 1.0f);
        const u64 b1 = __ballot(v1 > 1.0f);
        const int m = row0 + fg * 4 + j;
        if (fr == 0) {
          const u32 mask = (u32)((b0 >> (fg * 16)) & 0xFFFFu)
                         | ((u32)((b1 >> (fg * 16)) & 0xFFFFu) << 16);
          pbits[(((size_t)sel * 4096 + m) * 16 + head) * 2 + wc] = mask;
        }
        if (__builtin_fabsf(v0 - 1.0f) < TAU) {
          const u32 s = atomicAdd(&fls[0], 1u);   // LDS atomic
          if (s < BLK_FCAP) fls[2 + s] = ((u32)sel << 22) | ((u32)m << 10) | (u32)c0;
        }
        if (__builtin_fabsf(v1 - 1.0f) < TAU) {
          const u32 s = atomicAdd(&fls[0], 1u);
          if (s < BLK_FCAP) fls[2 + s] = ((u32)sel << 22) | ((u32)m << 10) | (u32)c1;
        }
      }
    }
  }
  __syncthreads();
  {
    const u32 cnt = fls[0] < BLK_FCAP ? fls[0] : BLK_FCAP;
    if (tid == 0) fls[1] = atomicAdd(flagcnt, cnt);  // ONE global atomic/block
    __syncthreads();
    const u32 base = fls[1];
    for (u32 i = tid; i < cnt; i += 256) {
      const u32 pos = base + i;
      if (pos < FCAP) flaglist[pos] = fls[2 + i];
    }
  }

  #pragma unroll
  for (int mf = 0; mf < 4; ++mf) {
    const int row0 = bm + wr * 64 + mf * 16 + fg * 4;
    #pragma unroll
    for (int nf = 0; nf < 2; ++nf) {
      const int col = bn + wc * 32 + nf * 16 + fr;
      const float bbv = bv[col];
      const int bb_ = row0 >> 11, t0 = row0 & 2047;
      const int hh = col >> 6, dd = col & 63;
      u16x4 o;
      o[0] = f2bf(acc[2][mf][nf][0] + bbv);
      o[1] = f2bf(acc[2][mf][nf][1] + bbv);
      o[2] = f2bf(acc[2][mf][nf][2] + bbv);
      o[3] = f2bf(acc[2][mf][nf][3] + bbv);
      *(u16x4*)&vT[(((size_t)(bb_ * 16 + hh)) * 64 + dd) * 2048 + t0] = o;
    }
  }
}

// ---------------------------------------------------------------------------
// Recompute near-threshold q/k entries with exact fp32 dot (verified).
// ---------------------------------------------------------------------------
__global__ __launch_bounds__(256) void fix_bits(
    const float* __restrict__ x,
    const float* __restrict__ Wq, const float* __restrict__ Wk,
    const float* __restrict__ bq, const float* __restrict__ bk,
    u32* __restrict__ pbits,
    const u32* __restrict__ flagcnt, const u32* __restrict__ flaglist)
{
  u32 cnt = *flagcnt;
  if (cnt > FCAP) cnt = FCAP;
  const int lane = threadIdx.x & 63;
  const u32 wid  = (blockIdx.x * 256 + threadIdx.x) >> 6;
  const u32 nw   = gridDim.x * 4;
  for (u32 i = wid; i < cnt; i += nw) {
    const u32 e = flaglist[i];
    const int which = e >> 22;
    const int m = (e >> 10) & 4095;
    const int n = e & 1023;
    const float* W    = which ? Wk : Wq;
    const float* bias = which ? bk : bq;
    float s = 0.f;
    #pragma unroll
    for (int j = 0; j < 16; ++j)
      s += x[(size_t)m * 1024 + lane + j * 64] * W[(size_t)n * 1024 + lane + j * 64];
    #pragma unroll
    for (int off = 32; off > 0; off >>= 1) s += __shfl_xor(s, off);
    const float val = s + bias[n];
    if (lane == 0) {
      const size_t idx = (((size_t)which * 4096 + m) * 16 + (n >> 6)) * 2 + ((n >> 5) & 1);
      const u32 bit = 1u << (n & 31);
      const bool oldb = (pbits[idx] >> (n & 31)) & 1u;
      const bool newb = val > 1.0f;
      if (oldb != newb) atomicXor(&pbits[idx], bit);
    }
  }
}

// ---------------------------------------------------------------------------
// MFMA attention, round 21 = verified round-18 kernel (dbuf vtb/kbt, single
// barrier/tile, wt_tab[65], in-register A-fragments, ones-MFMA Z, XCD
// swizzle, setprio, T14 V/kbt prefetch) + ONE change: QBLK 64->128.
// Each block covers 128 q-rows; wave w owns row-sets w*16 and 64+w*16.
// Every bfv fragment and every kbt pair is loaded ONCE and used for TWO
// weight-builds / MFMAs -> per-unit LDS traffic: kbt 16->8, vtb 8->4,
// writes 3->1.5 (~-31% on the pipe that bounds this kernel at ~59us).
// Grid 1024->512 (2 blocks/CU). Math bit-identical. (Round-20 per-thread
// global kbt reverted: 16 scattered VMEM loads/thread choked issue.)
// ---------------------------------------------------------------------------
__global__ __launch_bounds__(256) void attn_mfma(
    const u32* __restrict__ pbits, const u16* __restrict__ vT,
    u16* __restrict__ oh)
{
  __shared__ u16 vtb[2][64][72];
  __shared__ u64 kbt[2][68];
  __shared__ u32 wt_tab[65];

  const int tid = threadIdx.x, lane = tid & 63, w = tid >> 6;
  const int bid = ((blockIdx.x & 7) << 6) | (blockIdx.x >> 3);  // XCD swizzle, 512 blocks
  const int qt2 = bid & 15, bh = bid >> 4, b = bh >> 4, h = bh & 15;

  const int fr = lane & 15, fg = lane >> 4;

  if (tid < 65)
    wt_tab[tid] = __builtin_bit_cast(u32, exp2f((float)tid * 0.1803368801f));

  // two q-rows per thread: set0 = qt2*128 + w*16 + fr, set1 = +64
  const int qm0 = b * T_LEN + qt2 * 128 + w * 16 + fr;
  const size_t qb0 = (((size_t)qm0) * 16 + h) * 2;
  const size_t qb1 = (((size_t)(qm0 + 64)) * 16 + h) * 2;
  const u32 qlo0 = pbits[qb0];
  const u32 qhi0 = pbits[qb0 + 1];
  const u32 qlo1 = pbits[qb1];
  const u32 qhi1 = pbits[qb1 + 1];

  f32x4 acc0[4], acc1[4];
  #pragma unroll
  for (int nf = 0; nf < 4; ++nf) {
    acc0[nf] = (f32x4){0.f, 0.f, 0.f, 0.f};
    acc1[nf] = (f32x4){0.f, 0.f, 0.f, 0.f};
  }
  f32x4 accz0 = (f32x4){0.f, 0.f, 0.f, 0.f};
  f32x4 accz1 = (f32x4){0.f, 0.f, 0.f, 0.f};

  u16x8 ones;
  #pragma unroll
  for (int j = 0; j < 8; ++j) ones[j] = 0x3F80;  // bf16 1.0

  const u16* vbase = vT + (size_t)bh * 64 * T_LEN;
  const int sd = tid >> 2, sk = (tid & 3) << 3;

  // T14 prefetch registers (identical to round 18)
  u16x8 r0, r1;
  u64 kbr = 0;
#define VLOAD(KT)                                                       \
  {                                                                     \
    r0 = *(const u16x8*)&vbase[(size_t)sd * T_LEN + (KT) + sk];         \
    r1 = *(const u16x8*)&vbase[(size_t)sd * T_LEN + (KT) + sk + 32];    \
  }
#define KLOAD(KT)                                                       \
  if (tid < 64) {                                                       \
    const int km = b * T_LEN + (KT) + tid;                              \
    const size_t kb = (((size_t)(4096 + km)) * 16 + h) * 2;             \
    kbr = (u64)pbits[kb] | ((u64)pbits[kb + 1] << 32);                  \
  }

  VLOAD(0);
  KLOAD(0);

  int cur = 0;
  for (int kt = 0; kt < T_LEN; kt += 64) {
    *(u16x8*)&vtb[cur][sd][sk]      = r0;
    *(u16x8*)&vtb[cur][sd][sk + 32] = r1;
    if (tid < 64) kbt[cur][tid + (tid >> 4)] = kbr;
    if (kt + 64 < T_LEN) { VLOAD(kt + 64); KLOAD(kt + 64); }
    __syncthreads();   // single barrier per tile (dbuf pipeline)

    __builtin_amdgcn_s_setprio(1);
    #pragma unroll
    for (int ks = 0; ks < 2; ++ks) {
      // kbt pairs read ONCE, weights built for BOTH q-rows
      u16x8 af0, af1;
      u32* aw0 = (u32*)&af0;
      u32* aw1 = (u32*)&af1;
      #pragma unroll
      for (int p = 0; p < 4; ++p) {
        const int kk = ks * 32 + fg * 8 + p * 2;
        const int pidx = kk + (kk >> 4);        // padded kbt index
        const u64 kb0 = kbt[cur][pidx];
        const u64 kb1 = kbt[cur][pidx + 1];
        const u32 k0l = (u32)kb0, k0h = (u32)(kb0 >> 32);
        const u32 k1l = (u32)kb1, k1h = (u32)(kb1 >> 32);
        const int a0 = __builtin_popcount(qlo0 & k0l) + __builtin_popcount(qhi0 & k0h);
        const int a1 = __builtin_popcount(qlo0 & k1l) + __builtin_popcount(qhi0 & k1h);
        const int b0 = __builtin_popcount(qlo1 & k0l) + __builtin_popcount(qhi1 & k0h);
        const int b1 = __builtin_popcount(qlo1 & k1l) + __builtin_popcount(qhi1 & k1h);
        aw0[p] = (wt_tab[a1] & 0xFFFF0000u) | (wt_tab[a0] >> 16);
        aw1[p] = (wt_tab[b1] & 0xFFFF0000u) | (wt_tab[b0] >> 16);
      }
      // bfv read ONCE, used for both row-sets
      #pragma unroll
      for (int nf = 0; nf < 4; ++nf) {
        const u16x8 bfv = *(const u16x8*)&vtb[cur][nf * 16 + fr][ks * 32 + fg * 8];
        acc0[nf] = __builtin_amdgcn_mfma_f32_16x16x32_bf16(af0, bfv, acc0[nf], 0, 0, 0);
        acc1[nf] = __builtin_amdgcn_mfma_f32_16x16x32_bf16(af1, bfv, acc1[nf], 0, 0, 0);
      }
      accz0 = __builtin_amdgcn_mfma_f32_16x16x32_bf16(af0, ones, accz0, 0, 0, 0);
      accz1 = __builtin_amdgcn_mfma_f32_16x16x32_bf16(af1, ones, accz1, 0, 0, 0);
    }
    __builtin_amdgcn_s_setprio(0);
    cur ^= 1;
  }
#undef VLOAD
#undef KLOAD

  float iz0[4], iz1[4];
  #pragma unroll
  for (int j = 0; j < 4; ++j) {
    iz0[j] = 1.0f / accz0[j];
    iz1[j] = 1.0f / accz1[j];
  }

  #pragma unroll
  for (int nf = 0; nf < 4; ++nf) {
    const int col = h * 64 + nf * 16 + fr;
    #pragma unroll
    for (int j = 0; j < 4; ++j) {
      const int qrow = qt2 * 128 + w * 16 + fg * 4 + j;
      const size_t gq0 = (size_t)b * T_LEN + qrow;
      const size_t gq1 = gq0 + 64;
      oh[gq0 * 1024 + col] = f2bf(acc0[nf][j] * iz0[j]);
      oh[gq1 * 1024 + col] = f2bf(acc1[nf][j] * iz1[j]);
    }
  }
}

// ---------------------------------------------------------------------------
// Out projection: single-pass bf16 MFMA (verified round 6).
// ---------------------------------------------------------------------------
__global__ __launch_bounds__(256) void mfma_out(
    const u16* __restrict__ Ah, const u16* __restrict__ Bh,
    const float* __restrict__ bias, float* __restrict__ out)
{
  __shared__ u16 Ahs[2][128][32];
  __shared__ u16 Bhs[2][64][32];

  const int tid  = threadIdx.x;
  const int lane = tid & 63;
  const int w    = tid >> 6;
  const int wr   = w & 1;
  const int wc   = w >> 1;
  const int bm   = blockIdx.x * 128;
  const int bn   = blockIdx.y * 64;

  f32x4 acc[4][2];
  #pragma unroll
  for (int mf = 0; mf < 4; ++mf)
    #pragma unroll
    for (int nf = 0; nf < 2; ++nf) acc[mf][nf] = (f32x4){0.f, 0.f, 0.f, 0.f};

  const int sr = lane >> 2;
  const int sc = lane & 3;

#define STG(DST, SRC, TB, R0, KT)                                          \
  async16(&DST[(R0)][0],                                                   \
          &SRC[(size_t)((TB) + (R0) + sr) * 1024 + (KT) +                  \
               ((sc ^ ((((R0) + sr) >> 1) & 3)) << 3)]);

#define STAGE(B_, KT)                        \
  {                                          \
    STG(Ahs[B_], Ah, bm, w * 32, KT);        \
    STG(Ahs[B_], Ah, bm, w * 32 + 16, KT);   \
    STG(Bhs[B_], Bh, bn, w * 16, KT);        \
  }

  STAGE(0, 0);
  __syncthreads();

  const int fr = lane & 15;
  const int fg = lane >> 4;
  int cur = 0;

  for (int kt = 0; kt < 1024; kt += 32) {
    if (kt + 32 < 1024) STAGE(cur ^ 1, kt + 32);

    u16x8 a_h[4], b_h[2];
    #pragma unroll
    for (int mf = 0; mf < 4; ++mf) {
      const int row = wr * 64 + mf * 16 + fr;
      const int cs = (fg ^ ((row >> 1) & 3)) << 3;
      a_h[mf] = *(const u16x8*)&Ahs[cur][row][cs];
    }
    #pragma unroll
    for (int nf = 0; nf < 2; ++nf) {
      const int col = wc * 32 + nf * 16 + fr;
      const int cs = (fg ^ ((col >> 1) & 3)) << 3;
      b_h[nf] = *(const u16x8*)&Bhs[cur][col][cs];
    }
    #pragma unroll
    for (int mf = 0; mf < 4; ++mf)
      #pragma unroll
      for (int nf = 0; nf < 2; ++nf)
        acc[mf][nf] = __builtin_amdgcn_mfma_f32_16x16x32_bf16(a_h[mf], b_h[nf], acc[mf][nf], 0, 0, 0);
    __syncthreads();
    cur ^= 1;
  }
#undef STAGE
#undef STG

  #pragma unroll
  for (int mf = 0; mf < 4; ++mf) {
    const int row0 = bm + wr * 64 + mf * 16 + fg * 4;
    #pragma unroll
    for (int nf = 0; nf < 2; ++nf) {
      const int col = bn + wc * 32 + nf * 16 + fr;
      const float bb = bias[col];
      #pragma unroll
      for (int j = 0; j < 4; ++j)
        out[(size_t)(row0 + j) * 1024 + col] = acc[mf][nf][j] + bb;
    }
  }
}

// ---------------------------------------------------------------------------
extern "C" void kernel_launch(void* const* d_in, const int* in_sizes, int n_in,
                              void* d_out, int out_size, void* d_ws, size_t ws_size,
                              hipStream_t stream) {
  const float* x  = (const float*)d_in[0];
  const float* Wq = (const float*)d_in[1];
  const float* bq = (const float*)d_in[2];
  const float* Wk = (const float*)d_in[3];
  const float* bk = (const float*)d_in[4];
  const float* Wv = (const float*)d_in[5];
  const float* bv = (const float*)d_in[6];
  const float* Wo = (const float*)d_in[7];
  const float* bo = (const float*)d_in[8];
  float* out = (float*)d_out;

  char* ws = (char*)d_ws;
  u16* oh   = (u16*)ws;                // [0,8MB)
  u16* xh   = (u16*)(ws + 16 * MB);    // fp16 x, 8MB
  u16* vT   = (u16*)(ws + 32 * MB);    // bf16 vT, 8MB
  u16* Woh  = (u16*)(ws + 40 * MB);    // bf16 Wo, 2MB
  u32* pbits = (u32*)(ws + 44 * MB);
  u32* flagcnt  = (u32*)(ws + 45 * MB);
  u32* flaglist = (u32*)(ws + 45 * MB + 256);

  // d_out doubles as scratch for q/k/v fp16 weights (dead before out-proj).
  char* dob = (char*)d_out;
  u16* Wq16 = (u16*)dob;
  u16* Wk16 = (u16*)(dob + 2 * MB);
  u16* Wv16 = (u16*)(dob + 4 * MB);

  split_all<<<8192, 256, 0, stream>>>(x, Wq, Wk, Wv, Wo,
                                      xh, Wq16, Wk16, Wv16, Woh, flagcnt);

  dim3 g1(M_ROWS / 128, 1024 / 64);   // merged: one block does q+k+v
  mfma_qkv<<<g1, 256, 0, stream>>>(xh, Wq16, Wk16, Wv16,
                                   bq, bk, bv, pbits, flagcnt, flaglist, vT);

  fix_bits<<<256, 256, 0, stream>>>(x, Wq, Wk, bq, bk, pbits, flagcnt, flaglist);

  attn_mfma<<<512, 256, 0, stream>>>(pbits, vT, oh);

  dim3 g2(M_ROWS / 128, 1024 / 64);
  mfma_out<<<g2, 256, 0, stream>>>(oh, Woh, bo, out);
}